// Round 7
// baseline (203.397 us; speedup 1.0000x reference)
//
#include <hip/hip_runtime.h>

#define TOKENS 8192
#define IN_F   4096
#define OUT_F  4096

#define BM 128
#define BN 256
#define BK 64
#define NT (IN_F / BK)   // 64 K-tiles

typedef __attribute__((ext_vector_type(4))) float  f32x4;
typedef __attribute__((ext_vector_type(4))) int    i32x4;

typedef const __attribute__((address_space(1))) void gas_void;
typedef __attribute__((address_space(3))) void las_void;

// ---------------------------------------------------------------------------
// quant_x: per-token symmetric i8 quantization. One block (256 thr) per row.
// ---------------------------------------------------------------------------
__global__ __launch_bounds__(256) void quant_x_kernel(const float* __restrict__ x,
                                                      signed char* __restrict__ xq,
                                                      float* __restrict__ dx) {
    const int row  = blockIdx.x;
    const int tid  = threadIdx.x;
    const int lane = tid & 63;
    const int wv   = tid >> 6;
    const float* xr = x + (size_t)row * IN_F;

    float v[16];
#pragma unroll
    for (int k = 0; k < 4; ++k) {
        f32x4 t = *(const f32x4*)(xr + k * 1024 + tid * 4);
#pragma unroll
        for (int j = 0; j < 4; ++j) v[k * 4 + j] = t[j];
    }
    float m = 0.f;
#pragma unroll
    for (int j = 0; j < 16; ++j) m = fmaxf(m, fabsf(v[j]));
#pragma unroll
    for (int off = 32; off >= 1; off >>= 1) m = fmaxf(m, __shfl_xor(m, off));
    __shared__ float sm[4];
    if (lane == 0) sm[wv] = m;
    __syncthreads();
    m = fmaxf(fmaxf(sm[0], sm[1]), fmaxf(sm[2], sm[3]));

    const float inv = 127.0f / m;
    if (tid == 0) dx[row] = m * (1.0f / 127.0f);

    int* out = (int*)(xq + (size_t)row * IN_F);
#pragma unroll
    for (int k = 0; k < 4; ++k) {
        int p = 0;
#pragma unroll
        for (int j = 0; j < 4; ++j) {
            int q = (int)rintf(v[k * 4 + j] * inv);
            p |= (q & 0xff) << (8 * j);
        }
        out[k * 256 + tid] = p;
    }
}

// ---------------------------------------------------------------------------
// quant_w: per-out-row integer re-scale of ternary weights.
// ---------------------------------------------------------------------------
__global__ __launch_bounds__(256) void quant_w_kernel(const int* __restrict__ tern,
                                                      const float* __restrict__ scales,
                                                      signed char* __restrict__ wq,
                                                      float* __restrict__ dw) {
    const int o   = blockIdx.x;
    const int tid = threadIdx.x;
    const float* sr = scales + o * 32;

    float smax = 0.f;
#pragma unroll
    for (int g = 0; g < 32; ++g) smax = fmaxf(smax, sr[g]);
    if (tid == 0) dw[o] = smax * (1.0f / 127.0f);

    const int g  = tid >> 3;
    const int iq = (int)rintf(sr[g] * (127.0f / smax));

    const i32x4* tp = (const i32x4*)(tern + (size_t)o * IN_F + tid * 16);
    i32x4 out;
#pragma unroll
    for (int k = 0; k < 4; ++k) {
        i32x4 t = tp[k];
        int p = 0;
#pragma unroll
        for (int j = 0; j < 4; ++j) p |= ((t[j] * iq) & 0xff) << (8 * j);
        out[k] = p;
    }
    *(i32x4*)(wq + (size_t)o * IN_F + tid * 16) = out;
}

// ---------------------------------------------------------------------------
// C[M][N] = (xq . wq^T) * dx[m] * dw[n],  i8 MFMA 16x16x64, i32 acc.
// 128x256 tile, BK=64, 8 waves (2M x 4N), per-wave 64x64 -> acc 64 regs.
// Goal: unified VGPR+AGPR <= 128 -> 2 blocks/CU (async cross-block overlap).
// LDS 48 KiB/block: As[2][128][64] + Bs[2][256][64] i8, row-pair swizzle:
//   logical (r,c) at phys (r>>1)*128 + ((((r&1)<<6)|c) ^ (((r>>1)&7)<<4))
// (involution applied to stage-source and read-addr; 2-way banks = free).
// Schedule per K-tile (r5-style invariants):
//   P1: rdA0-3, rdB0-1 (6); stage t+1.B0 -> bufn; QUAD(ni01)
//   P2: rdB2-3 (2);         stage t+1.B1 -> bufn; QUAD(ni23)
//   bar#1 (all buf-t reads lgkm-complete before it, via QUAD uses)
//   P3: stage t+2.A -> buf; vmcnt(1) [keeps t+2.A in flight]; bar#2
// ---------------------------------------------------------------------------

#define QUAD(NI0)                                                              \
  do {                                                                         \
    __builtin_amdgcn_s_setprio(1);                                             \
    _Pragma("unroll") for (int mi = 0; mi < 4; ++mi)                           \
      _Pragma("unroll") for (int ni = 0; ni < 2; ++ni)                         \
          acc[mi][(NI0)+ni] = __builtin_amdgcn_mfma_i32_16x16x64_i8(           \
              a[mi], b[(NI0)+ni], acc[mi][(NI0)+ni], 0, 0, 0);                 \
    __builtin_amdgcn_s_setprio(0);                                             \
  } while (0)

__global__ __launch_bounds__(512, 4) void gemm_i8_kernel(
        const signed char* __restrict__ A,
        const signed char* __restrict__ B,
        const float* __restrict__ dX,
        const float* __restrict__ dW,
        float* __restrict__ C) {
    __shared__ __align__(16) signed char As[2 * 128 * 64];
    __shared__ __align__(16) signed char Bs[2 * 256 * 64];

    const int tid  = threadIdx.x;
    const int wave = tid >> 6;
    const int lane = tid & 63;
    const int wm   = wave >> 2;        // 0-1
    const int wn   = wave & 3;         // 0-3
    const int lg   = lane >> 4;        // 0-3
    const int lr   = lane & 15;        // 0-15

    // XCD swizzle, bn-major within XCD: each XCD sees 2 bn-panels (L2-resident)
    int bid = blockIdx.x;
    const int swz = (bid & 7) * 128 + (bid >> 3);   // 1024 % 8 == 0 -> bijective
    const int bn = swz >> 6;           // 0-15
    const int bm = swz & 63;           // 0-63

    const size_t a_row0 = (size_t)bm * BM;
    const size_t b_row0 = (size_t)bn * BN;

    // staging: unit = 8 KB (128 rows x 64), 1x16B load/thread.
    // phys p=tid*16 holds logical (r,c): x=(tid&7)^((tid>>3)&7),
    // r=((tid>>3)<<1)|(x>>2), c=(x&3)<<4  (inverse of the read swizzle).
    const int sx  = (tid & 7) ^ ((tid >> 3) & 7);
    const int s_r = ((tid >> 3) << 1) | ((sx >> 2) & 1);
    const int s_c = (sx & 3) << 4;

    auto stage_unit = [&](int buf, int which, int k0) {
        // which: 0 = A rows 0-127, 1 = B rows 0-127, 2 = B rows 128-255
        const signed char* G = (which == 0) ? A : B;
        const size_t grow0 = (which == 0) ? a_row0 : (b_row0 + (which == 2 ? 128 : 0));
        signed char* dstb = (which == 0) ? (As + buf * 8192)
                                         : (Bs + buf * 16384 + (which == 2 ? 8192 : 0));
        const signed char* src = G + (grow0 + s_r) * IN_F + k0 + s_c;
        __builtin_amdgcn_global_load_lds((gas_void*)src,
                                         (las_void*)(dstb + (wave << 10)), 16, 0, 0);
    };

    i32x4 acc[4][4] = {};
    i32x4 a[4], b[4];

    // precomputed physical read offsets (loop-invariant per thread)
    auto physoff = [&](int r, int c0) {
        return ((r >> 1) << 7) + (((((r & 1) << 6) | c0) ^ (((r >> 1) & 7) << 4)));
    };
    int pA[4], pB[4];
#pragma unroll
    for (int mi = 0; mi < 4; ++mi) pA[mi] = physoff(wm * 64 + mi * 16 + lr, lg << 4);
#pragma unroll
    for (int ni = 0; ni < 4; ++ni) pB[ni] = physoff(wn * 64 + ni * 16 + lr, lg << 4);

    // ---- prologue: tile0 (A,B0,B1) + tile1.A; drain tile0, keep 1 in flight
    stage_unit(0, 0, 0); stage_unit(0, 1, 0); stage_unit(0, 2, 0);
    stage_unit(1, 0, BK);
    asm volatile("s_waitcnt vmcnt(1)" ::: "memory");
    __builtin_amdgcn_sched_barrier(0);
    __builtin_amdgcn_s_barrier();
    __builtin_amdgcn_sched_barrier(0);

    for (int t = 0; t < NT; ++t) {
        const int buf   = t & 1;
        const int abase = buf * 8192;
        const int bbase = buf * 16384;
        const int bufn  = buf ^ 1;

        // ---- P1: rdA0-3, rdB0-1; stage t+1.B0; QUAD(ni01)
#pragma unroll
        for (int mi = 0; mi < 4; ++mi) a[mi] = *(const i32x4*)&As[abase + pA[mi]];
        b[0] = *(const i32x4*)&Bs[bbase + pB[0]];
        b[1] = *(const i32x4*)&Bs[bbase + pB[1]];
        if (t + 1 < NT) stage_unit(bufn, 1, (t + 1) * BK);
        QUAD(0);

        // ---- P2: rdB2-3; stage t+1.B1; QUAD(ni23)
        b[2] = *(const i32x4*)&Bs[bbase + pB[2]];
        b[3] = *(const i32x4*)&Bs[bbase + pB[3]];
        if (t + 1 < NT) stage_unit(bufn, 2, (t + 1) * BK);
        QUAD(2);

        __builtin_amdgcn_sched_barrier(0);
        __builtin_amdgcn_s_barrier();                  // #1: all buf-t reads done
        __builtin_amdgcn_sched_barrier(0);

        // ---- P3: stage t+2.A into freed As[buf]; counted vmcnt
        if (t + 2 < NT) {
            stage_unit(buf, 0, (t + 2) * BK);
            asm volatile("s_waitcnt vmcnt(1)" ::: "memory");
        } else if (t + 1 < NT) {
            asm volatile("s_waitcnt vmcnt(0)" ::: "memory");
        }
        __builtin_amdgcn_sched_barrier(0);
        __builtin_amdgcn_s_barrier();                  // #2: t+1 units visible
        __builtin_amdgcn_sched_barrier(0);
    }

    // ---- epilogue: out = acc * dx[row] * dw[col]; C/D col=lane&15, row=lg*4+j
    float dwc[4];
#pragma unroll
    for (int ni = 0; ni < 4; ++ni) dwc[ni] = dW[b_row0 + wn * 64 + ni * 16 + lr];

    float* Cp = C + (a_row0 + wm * 64) * (size_t)OUT_F + b_row0 + wn * 64;
#pragma unroll
    for (int mi = 0; mi < 4; ++mi) {
#pragma unroll
        for (int j = 0; j < 4; ++j) {
            const int r = mi * 16 + lg * 4 + j;
            const float dxr = dX[a_row0 + wm * 64 + r];
#pragma unroll
            for (int ni = 0; ni < 4; ++ni)
                Cp[(size_t)r * OUT_F + ni * 16 + lr] =
                    (float)acc[mi][ni][j] * dxr * dwc[ni];
        }
    }
}

extern "C" void kernel_launch(void* const* d_in, const int* in_sizes, int n_in,
                              void* d_out, int out_size, void* d_ws, size_t ws_size,
                              hipStream_t stream) {
    const float* x      = (const float*)d_in[0];
    const int*   tern   = (const int*)d_in[1];
    const float* scales = (const float*)d_in[2];

    signed char* xq = (signed char*)d_ws;
    signed char* wq = xq + (size_t)TOKENS * IN_F;
    float*       dx = (float*)(wq + (size_t)OUT_F * IN_F);
    float*       dw = dx + TOKENS;

    quant_x_kernel<<<TOKENS, 256, 0, stream>>>(x, xq, dx);
    quant_w_kernel<<<OUT_F, 256, 0, stream>>>(tern, scales, wq, dw);

    dim3 grid((TOKENS / BM) * (OUT_F / BN));   // 64*16 = 1024
    gemm_i8_kernel<<<grid, 512, 0, stream>>>(xq, wq, dx, dw, (float*)d_out);
}

// Round 8
// 179.796 us; speedup vs baseline: 1.1313x; 1.1313x over previous
//
#include <hip/hip_runtime.h>

#define TOKENS 8192
#define IN_F   4096
#define OUT_F  4096

#define BM 256
#define BN 256
#define BK 64
#define NT (IN_F / BK)   // 64 K-tiles

typedef __attribute__((ext_vector_type(4))) float  f32x4;
typedef __attribute__((ext_vector_type(4))) int    i32x4;

typedef const __attribute__((address_space(1))) void gas_void;
typedef __attribute__((address_space(3))) void las_void;

// ---------------------------------------------------------------------------
// quant_x: per-token symmetric i8 quantization. One block (256 thr) per row.
// ---------------------------------------------------------------------------
__global__ __launch_bounds__(256) void quant_x_kernel(const float* __restrict__ x,
                                                      signed char* __restrict__ xq,
                                                      float* __restrict__ dx) {
    const int row  = blockIdx.x;
    const int tid  = threadIdx.x;
    const int lane = tid & 63;
    const int wv   = tid >> 6;
    const float* xr = x + (size_t)row * IN_F;

    float v[16];
#pragma unroll
    for (int k = 0; k < 4; ++k) {
        f32x4 t = *(const f32x4*)(xr + k * 1024 + tid * 4);
#pragma unroll
        for (int j = 0; j < 4; ++j) v[k * 4 + j] = t[j];
    }
    float m = 0.f;
#pragma unroll
    for (int j = 0; j < 16; ++j) m = fmaxf(m, fabsf(v[j]));
#pragma unroll
    for (int off = 32; off >= 1; off >>= 1) m = fmaxf(m, __shfl_xor(m, off));
    __shared__ float sm[4];
    if (lane == 0) sm[wv] = m;
    __syncthreads();
    m = fmaxf(fmaxf(sm[0], sm[1]), fmaxf(sm[2], sm[3]));

    const float inv = 127.0f / m;
    if (tid == 0) dx[row] = m * (1.0f / 127.0f);

    int* out = (int*)(xq + (size_t)row * IN_F);
#pragma unroll
    for (int k = 0; k < 4; ++k) {
        int p = 0;
#pragma unroll
        for (int j = 0; j < 4; ++j) {
            int q = (int)rintf(v[k * 4 + j] * inv);
            p |= (q & 0xff) << (8 * j);
        }
        out[k * 256 + tid] = p;
    }
}

// ---------------------------------------------------------------------------
// quant_w: per-out-row integer re-scale of ternary weights.
// ---------------------------------------------------------------------------
__global__ __launch_bounds__(256) void quant_w_kernel(const int* __restrict__ tern,
                                                      const float* __restrict__ scales,
                                                      signed char* __restrict__ wq,
                                                      float* __restrict__ dw) {
    const int o   = blockIdx.x;
    const int tid = threadIdx.x;
    const float* sr = scales + o * 32;

    float smax = 0.f;
#pragma unroll
    for (int g = 0; g < 32; ++g) smax = fmaxf(smax, sr[g]);
    if (tid == 0) dw[o] = smax * (1.0f / 127.0f);

    const int g  = tid >> 3;
    const int iq = (int)rintf(sr[g] * (127.0f / smax));

    const i32x4* tp = (const i32x4*)(tern + (size_t)o * IN_F + tid * 16);
    i32x4 out;
#pragma unroll
    for (int k = 0; k < 4; ++k) {
        i32x4 t = tp[k];
        int p = 0;
#pragma unroll
        for (int j = 0; j < 4; ++j) p |= ((t[j] * iq) & 0xff) << (8 * j);
        out[k] = p;
    }
    *(i32x4*)(wq + (size_t)o * IN_F + tid * 16) = out;
}

// ---------------------------------------------------------------------------
// C[M][N] = (xq . wq^T) * dx[m] * dw[n],  i8 MFMA 16x16x64, i32 acc.
// 256x256 tile, BK=64, 8 waves (2M x 4N), per-wave 128x64, acc 128 AGPR.
// r8: SINGLE-REGION K-loop, triple-buffered LDS (3 x 32KB = 96 KiB):
//   iter t: [vmcnt(4) gate; barrier] then ONE region containing
//     12 ds_read_b128 (buf t%3) | stage tile t+2 -> buf (t+2)%3 (4 gloads)
//     | 32 MFMA  -- no intra-tile barrier, scheduler overlaps LDS and MFMA.
// Hazards: stage(t+2) buf last read at iter t-1, ordered by iter-t barrier;
// vmcnt(4) drains stage(t) (FIFO, stage(t+1)'s 4 remain in flight).
// LDS layout (r7-verified conflict-free): logical 64B rows packed as 128B
// phys row-pairs with XOR swizzle:
//   phys(r,c) = (r>>1)*128 + ((((r&1)<<6)|c) ^ (((r>>1)&7)<<4))
// ---------------------------------------------------------------------------

#define QUAD(MI0, NI0)                                                         \
  do {                                                                         \
    __builtin_amdgcn_s_setprio(1);                                             \
    _Pragma("unroll") for (int mi = 0; mi < 4; ++mi)                           \
      _Pragma("unroll") for (int ni = 0; ni < 2; ++ni)                         \
          acc[(MI0)+mi][(NI0)+ni] = __builtin_amdgcn_mfma_i32_16x16x64_i8(     \
              a[(MI0)+mi], b[(NI0)+ni], acc[(MI0)+mi][(NI0)+ni], 0, 0, 0);     \
    __builtin_amdgcn_s_setprio(0);                                             \
  } while (0)

__global__ __launch_bounds__(512, 2) void gemm_i8_kernel(
        const signed char* __restrict__ A,
        const signed char* __restrict__ B,
        const float* __restrict__ dX,
        const float* __restrict__ dW,
        float* __restrict__ C) {
    __shared__ __align__(16) signed char As[3 * 16384];
    __shared__ __align__(16) signed char Bs[3 * 16384];

    const int tid  = threadIdx.x;
    const int wave = tid >> 6;
    const int lane = tid & 63;
    const int wm   = wave >> 2;        // 0-1
    const int wn   = wave & 3;         // 0-3
    const int lg   = lane >> 4;        // 0-3
    const int lr   = lane & 15;        // 0-15

    int bid = blockIdx.x;
    bid = (bid & 7) * (512 >> 3) + (bid >> 3);   // XCD swizzle, 512%8==0
    const int bm = bid >> 4;           // 0-31
    const int bn = bid & 15;           // 0-15

    const size_t a_row0 = (size_t)bm * BM;
    const size_t b_row0 = (size_t)bn * BN;

    // staging: unit = 8KB = 128 logical rows x 64B, 1x16B load/thread.
    // thread tid -> phys byte tid*16; inverse-swizzled source (rule #21):
    const int sx  = (tid & 7) ^ ((tid >> 3) & 7);
    const int s_r = ((tid >> 3) << 1) | ((sx >> 2) & 1);   // local row 0..127
    const int s_c = (sx & 3) << 4;                         // col 0..48

    // which: 0/1 = A half h, 2/3 = B half h-2
    auto stage_unit = [&](int buf, int which, int k0) {
        const int h = which & 1;
        const signed char* G = (which < 2) ? A : B;
        const size_t grow0 = ((which < 2) ? a_row0 : b_row0) + (size_t)h * 128;
        signed char* dstb = ((which < 2) ? As : Bs) + buf * 16384 + h * 8192;
        const signed char* src = G + (grow0 + s_r) * IN_F + k0 + s_c;
        __builtin_amdgcn_global_load_lds((gas_void*)src,
                                         (las_void*)(dstb + (wave << 10)), 16, 0, 0);
    };

    i32x4 acc[8][4] = {};
    i32x4 a[8], b[4];

    auto physoff = [&](int r, int c0) {
        return ((r >> 1) << 7) + (((((r & 1) << 6) | c0) ^ (((r >> 1) & 7) << 4)));
    };
    int pA[8], pB[4];
#pragma unroll
    for (int mi = 0; mi < 8; ++mi) pA[mi] = physoff(wm * 128 + mi * 16 + lr, lg << 4);
#pragma unroll
    for (int ni = 0; ni < 4; ++ni) pB[ni] = physoff(wn * 64 + ni * 16 + lr, lg << 4);

    // ---- prologue: stage tiles 0 and 1 (buffers 0,1); gates handled in-loop
    stage_unit(0, 0, 0); stage_unit(0, 1, 0); stage_unit(0, 2, 0); stage_unit(0, 3, 0);
    stage_unit(1, 0, BK); stage_unit(1, 1, BK); stage_unit(1, 2, BK); stage_unit(1, 3, BK);

    int cur = 0;
    for (int t = 0; t < NT; ++t) {
        // gate: drain stage(t) (oldest 4); stage(t+1)'s 4 stay in flight
        if (t + 1 < NT) {
            asm volatile("s_waitcnt vmcnt(4)" ::: "memory");
        } else {
            asm volatile("s_waitcnt vmcnt(0)" ::: "memory");
        }
        __builtin_amdgcn_sched_barrier(0);
        __builtin_amdgcn_s_barrier();    // buf cur staged; buf (t+2)%3 free
        __builtin_amdgcn_sched_barrier(0);

        const int abase = cur * 16384;
        int s2 = cur + 2; if (s2 >= 3) s2 -= 3;

        // ---- ONE region: reads | staging | MFMAs (scheduler interleaves)
#pragma unroll
        for (int mi = 0; mi < 8; ++mi) a[mi] = *(const i32x4*)&As[abase + pA[mi]];
#pragma unroll
        for (int ni = 0; ni < 4; ++ni) b[ni] = *(const i32x4*)&Bs[abase + pB[ni]];

        if (t + 2 < NT) {
            const int k2 = (t + 2) * BK;
            stage_unit(s2, 0, k2); stage_unit(s2, 1, k2);
            stage_unit(s2, 2, k2); stage_unit(s2, 3, k2);
        }

        QUAD(0, 0); QUAD(0, 2); QUAD(4, 0); QUAD(4, 2);

        cur = (cur == 2) ? 0 : cur + 1;
    }

    // ---- epilogue: out = acc * dx[row] * dw[col]; C/D col=lane&15, row=lg*4+j
    float dwc[4];
#pragma unroll
    for (int ni = 0; ni < 4; ++ni) dwc[ni] = dW[b_row0 + wn * 64 + ni * 16 + lr];

    float* Cp = C + (a_row0 + wm * 128) * (size_t)OUT_F + b_row0 + wn * 64;
#pragma unroll
    for (int mi = 0; mi < 8; ++mi) {
#pragma unroll
        for (int j = 0; j < 4; ++j) {
            const int r = mi * 16 + lg * 4 + j;
            const float dxr = dX[a_row0 + wm * 128 + r];
#pragma unroll
            for (int ni = 0; ni < 4; ++ni)
                Cp[(size_t)r * OUT_F + ni * 16 + lr] =
                    (float)acc[mi][ni][j] * dxr * dwc[ni];
        }
    }
}

extern "C" void kernel_launch(void* const* d_in, const int* in_sizes, int n_in,
                              void* d_out, int out_size, void* d_ws, size_t ws_size,
                              hipStream_t stream) {
    const float* x      = (const float*)d_in[0];
    const int*   tern   = (const int*)d_in[1];
    const float* scales = (const float*)d_in[2];

    signed char* xq = (signed char*)d_ws;
    signed char* wq = xq + (size_t)TOKENS * IN_F;
    float*       dx = (float*)(wq + (size_t)OUT_F * IN_F);
    float*       dw = dx + TOKENS;

    quant_x_kernel<<<TOKENS, 256, 0, stream>>>(x, xq, dx);
    quant_w_kernel<<<OUT_F, 256, 0, stream>>>(tern, scales, wq, dw);

    dim3 grid((TOKENS / BM) * (OUT_F / BN));   // 32*16 = 512
    gemm_i8_kernel<<<grid, 512, 0, stream>>>(xq, wq, dx, dw, (float*)d_out);
}